// Round 7
// baseline (409.749 us; speedup 1.0000x reference)
//
#include <hip/hip_runtime.h>
#include <math.h>

#define N_BOX 8192
#define NT 1024
#define MAX_TOPK 128
#define IOU_THR 0.3f
#define M_TARGET 400u
#define CAP 1024
#define BIN_SHIFT 19      // top 13 bits -> 8192 bins
#define R_AMP 8           // amplification factor (attribution round)

// ---- ws layout ----
#define WS_BOXES_OFF 0                                  // 128 KB float4[8192]
#define WS_KEYS_OFF  (N_BOX * 16)                       // 32 KB  u32[8192]
#define WS_CAND_OFF  (WS_KEYS_OFF + N_BOX * 4)          // 8 KB   u64[CAP]
#define WS_SORT_OFF  (WS_CAND_OFF + CAP * 8)            // 8 KB   u64[CAP]
#define WS_SBOX_OFF  (WS_SORT_OFF + CAP * 8)            // 16 KB  float4[CAP]
#define WS_KEEP_OFF  (WS_SBOX_OFF + CAP * 16)           // 512 B  int[MAX_TOPK]
#define WS_META_OFF  (WS_KEEP_OFF + MAX_TOPK * 4)       // int[2]: C, nkept

__device__ __forceinline__ float fxor(float f, unsigned z) {
    return __uint_as_float(__float_as_uint(f) ^ z);
}

// ---------------- K1: decode + 32-bit sort-key build (x R_AMP) ----------------
__global__ void decode_kernel(const float* __restrict__ x,
                              const float* __restrict__ y,
                              const float* __restrict__ anchors,
                              float4* __restrict__ boxes,
                              unsigned* __restrict__ keys,
                              unsigned zero_arg)
{
#pragma clang fp contract(off)
    int i = blockIdx.x * blockDim.x + threadIdx.x;
    if (i >= N_BOX) return;

    float xv0 = x[i];
    const float2* yr = (const float2*)(y + i * 18);
    float2 ya = yr[0];
    float2 yb = yr[1];
    float2 an = ((const float2*)anchors)[i];
    const float inv128 = 0.0078125f;

#pragma unroll 1
    for (int rep = 0; rep < R_AMP; ++rep) {
        unsigned z = zero_arg & (unsigned)rep;          // == 0, opaque
        float xv = fxor(xv0, z);
        float s = 1.0f / (1.0f + expf(-xv));
        keys[i] = ~(__float_as_uint(s) | 0x80000000u);

        float cx = fxor(ya.x, z) * inv128 + an.x;
        float cy = fxor(ya.y, z) * inv128 + an.y;
        float w2 = (fxor(yb.x, z) * inv128) * 0.5f;
        float h2 = (fxor(yb.y, z) * inv128) * 0.5f;
        boxes[i] = make_float4(cx - w2, cy - h2, cx + w2, cy + h2);
    }
}

// ---------------- K2a: histogram + scan + compact (x R_AMP) ----------------
__global__ __launch_bounds__(NT)
void select_kernel(const unsigned* __restrict__ keys,
                   unsigned long long* __restrict__ g_cand,
                   int* __restrict__ g_meta,
                   unsigned zero_arg)
{
    __shared__ unsigned s_hist[N_BOX];              // 32 KB
    __shared__ unsigned s_waveexcl[17];
    __shared__ unsigned long long s_cand[CAP];      // 8 KB
    __shared__ int s_cnt, s_B, s_C;

    const int tid = threadIdx.x;
    const int lane = tid & 63;
    const int wv = tid >> 6;

    const uint4* kp = (const uint4*)keys;
    uint4 ka = kp[tid * 2 + 0];
    uint4 kb = kp[tid * 2 + 1];
    unsigned myk0[8] = {ka.x, ka.y, ka.z, ka.w, kb.x, kb.y, kb.z, kb.w};

#pragma unroll 1
    for (int rep = 0; rep < R_AMP; ++rep) {
        unsigned z = zero_arg & (unsigned)rep;          // == 0, opaque
        unsigned myk[8];
#pragma unroll
        for (int k = 0; k < 8; k++) myk[k] = myk0[k] ^ z;

        if (tid == 0) s_cnt = 0;
        {
            uint4 zz = make_uint4(0u, 0u, 0u, 0u);
            uint4* hp = (uint4*)s_hist;
            hp[tid * 2 + 0] = zz;
            hp[tid * 2 + 1] = zz;
            s_cand[tid] = ~0ull;
        }
        __syncthreads();

#pragma unroll
        for (int k = 0; k < 8; k++)
            atomicAdd(&s_hist[myk[k] >> BIN_SHIFT], 1u);
        __syncthreads();

        uint4 h0 = ((const uint4*)s_hist)[tid * 2 + 0];
        uint4 h1 = ((const uint4*)s_hist)[tid * 2 + 1];
        unsigned binv[8] = {h0.x, h0.y, h0.z, h0.w, h1.x, h1.y, h1.z, h1.w};
        unsigned csum = binv[0] + binv[1] + binv[2] + binv[3]
                      + binv[4] + binv[5] + binv[6] + binv[7];

        unsigned incl = csum;
        for (int off = 1; off < 64; off <<= 1) {
            unsigned n = __shfl_up(incl, off);
            if (lane >= off) incl += n;
        }
        if (lane == 63) s_waveexcl[wv + 1] = incl;
        __syncthreads();
        if (wv == 0) {
            unsigned t = (lane < 16) ? s_waveexcl[lane + 1] : 0u;
            unsigned v = t;
            for (int off = 1; off < 16; off <<= 1) {
                unsigned n = __shfl_up(v, off);
                if (lane >= off) v += n;
            }
            if (lane < 16) s_waveexcl[lane] = v - t;
        }
        __syncthreads();

        unsigned myexcl = s_waveexcl[wv] + incl - csum;
        if (myexcl < M_TARGET && myexcl + csum >= M_TARGET) {
            unsigned run = myexcl;
#pragma unroll
            for (int k = 0; k < 8; k++) {
                run += binv[k];
                if (run >= M_TARGET) { s_B = tid * 8 + k; s_C = (int)run; break; }
            }
        }
        __syncthreads();

        const int B = s_B;
#pragma unroll
        for (int k = 0; k < 8; k++) {
            if ((int)(myk[k] >> BIN_SHIFT) <= B) {
                int p = atomicAdd(&s_cnt, 1);
                if (p < CAP)
                    s_cand[p] = (((unsigned long long)myk[k]) << 32) | (unsigned)(tid * 8 + k);
            }
        }
        __syncthreads();

        g_cand[tid] = s_cand[tid];
        if (tid == 0) {
            int C = s_C; if (C > CAP) C = CAP;
            g_meta[0] = C;
        }
        __syncthreads();
    }
}

// ---------------- K2b: rank sort + box gather (x R_AMP) ----------------
__global__ __launch_bounds__(NT)
void sortgather_kernel(const unsigned long long* __restrict__ g_cand,
                       const float4* __restrict__ boxes,
                       unsigned long long* __restrict__ g_sorted,
                       float4* __restrict__ g_sbox,
                       const int* __restrict__ g_meta,
                       unsigned zero_arg)
{
    __shared__ unsigned long long s_cand[CAP];      // 8 KB
    __shared__ unsigned long long s_sorted[CAP];    // 8 KB

    const int tid = threadIdx.x;
    const int C = g_meta[0];

#pragma unroll 1
    for (int rep = 0; rep < R_AMP; ++rep) {
        unsigned z = zero_arg & (unsigned)rep;          // == 0, opaque
        s_cand[tid] = g_cand[tid ^ z];
        __syncthreads();

        const int Cpad = (C + 7) & ~7;
        if (tid < C) {
            unsigned long long me = s_cand[tid];
            int rank = 0;
            const ulonglong2* cp = (const ulonglong2*)s_cand;
            for (int j = 0; j < Cpad; j += 8) {
                ulonglong2 a = cp[(j >> 1) + 0];
                ulonglong2 b = cp[(j >> 1) + 1];
                ulonglong2 d = cp[(j >> 1) + 2];
                ulonglong2 e = cp[(j >> 1) + 3];
                rank += (a.x < me) + (a.y < me) + (b.x < me) + (b.y < me)
                      + (d.x < me) + (d.y < me) + (e.x < me) + (e.y < me);
            }
            s_sorted[rank] = me;
        }
        __syncthreads();

        if (tid < C) {
            unsigned long long kk = s_sorted[tid];
            int idx = (int)(unsigned)(kk & 0xFFFFFFFFull) ^ (int)z;
            g_sorted[tid] = kk;
            g_sbox[tid] = boxes[idx];
        }
        __syncthreads();
    }
}

// ---------------- K2c: single-wave NMS (x R_AMP) ----------------
__global__ __launch_bounds__(64)
void nms_kernel(const unsigned long long* __restrict__ g_sorted,
                const float4* __restrict__ g_sbox,
                int* __restrict__ g_keep,
                int* __restrict__ g_meta,
                int top_k,
                unsigned zero_arg)
{
#pragma clang fp contract(off)
    const int lane = threadIdx.x;
    const int C = g_meta[0];

#pragma unroll 1
    for (int rep = 0; rep < R_AMP; ++rep) {
        unsigned z = zero_arg & (unsigned)rep;          // == 0, opaque
        float k0x1 = 0.f, k0y1 = 0.f, k0x2 = 0.f, k0y2 = 0.f, k0a = 0.f;
        float k1x1 = 0.f, k1y1 = 0.f, k1x2 = 0.f, k1y2 = 0.f, k1a = 0.f;
        int nkept = 0;
        int base = 0;
        float4 bb = make_float4(0.f, 0.f, 0.f, 0.f);
        int bidx = 0;
        if (lane < C) {
            int g0 = lane ^ (int)z;
            bb = g_sbox[g0];
            bidx = (int)(unsigned)(g_sorted[g0] & 0xFFFFFFFFull);
        }

        int c = 0;
        while (c < C && nkept < top_k) {
            int p = c - base;
            if (p == 64) {
                base += 64; p = 0;
                int g = (base + lane) ^ (int)z;
                if (g < C) {
                    bb = g_sbox[g];
                    bidx = (int)(unsigned)(g_sorted[g] & 0xFFFFFFFFull);
                }
            }
            float cx1 = __shfl(bb.x, p);
            float cy1 = __shfl(bb.y, p);
            float cx2 = __shfl(bb.z, p);
            float cy2 = __shfl(bb.w, p);
            int  cidx = __shfl(bidx, p);
            float carea = (cx2 - cx1) * (cy2 - cy1);

            bool hit = false;
            if (lane < nkept) {
                float iw = fmaxf(fminf(k0x2, cx2) - fmaxf(k0x1, cx1), 0.0f);
                float ih = fmaxf(fminf(k0y2, cy2) - fmaxf(k0y1, cy1), 0.0f);
                float inter = iw * ih;
                float iou = inter / (k0a + carea - inter);
                if (iou > IOU_THR) hit = true;
            }
            if (lane + 64 < nkept) {
                float iw = fmaxf(fminf(k1x2, cx2) - fmaxf(k1x1, cx1), 0.0f);
                float ih = fmaxf(fminf(k1y2, cy2) - fmaxf(k1y1, cy1), 0.0f);
                float inter = iw * ih;
                float iou = inter / (k1a + carea - inter);
                if (iou > IOU_THR) hit = true;
            }
            unsigned long long m = __ballot(hit);
            if (m == 0ull) {
                if (nkept < 64) {
                    if (lane == nkept) {
                        k0x1 = cx1; k0y1 = cy1; k0x2 = cx2; k0y2 = cy2; k0a = carea;
                    }
                } else {
                    if (lane == nkept - 64) {
                        k1x1 = cx1; k1y1 = cy1; k1x2 = cx2; k1y2 = cy2; k1a = carea;
                    }
                }
                if (lane == 0) g_keep[nkept] = cidx;
                nkept++;
            }
            c++;
        }
        if (lane == 0) g_meta[1] = nkept;
    }
}

// ---------------- K2d: output gather (x R_AMP) ----------------
__global__ __launch_bounds__(NT)
void output_kernel(const float* __restrict__ x,
                   const float* __restrict__ y,
                   const float* __restrict__ anchors,
                   const int* __restrict__ g_keep,
                   const int* __restrict__ g_meta,
                   float* __restrict__ out,
                   int top_k,
                   unsigned zero_arg)
{
#pragma clang fp contract(off)
    const int t = threadIdx.x;
    const int total = top_k * 8;
    if (t >= total) return;

    const int nkept = g_meta[1];
    const float inv128 = 0.0078125f;
    int r = t >> 3;
    int col = t & 7;

#pragma unroll 1
    for (int rep = 0; rep < R_AMP; ++rep) {
        unsigned z = zero_arg & (unsigned)rep;          // == 0, opaque
        float v = 0.0f;
        if (r < nkept) {
            int idx = g_keep[r] ^ (int)z;
            if (col == 0) {
                v = 1.0f / (1.0f + expf(-x[idx]));
            } else {
                int j = (col <= 3) ? (col - 1) : ((col <= 5) ? col : (col + 2));
                float a;
                if (j == 2) a = 0.0f;
                else        a = (j & 1) ? anchors[idx * 2 + 1] : anchors[idx * 2 + 0];
                v = y[idx * 18 + j] * inv128 + a;
            }
        }
        out[t] = v;
    }
}

extern "C" void kernel_launch(void* const* d_in, const int* in_sizes, int n_in,
                              void* d_out, int out_size, void* d_ws, size_t ws_size,
                              hipStream_t stream) {
    const float* x       = (const float*)d_in[0];   // (1, 8192, 1)
    const float* y       = (const float*)d_in[1];   // (1, 8192, 18)
    const float* anchors = (const float*)d_in[2];   // (8192, 2)
    float* out = (float*)d_out;                     // (top_k, 8) f32

    char* ws = (char*)d_ws;
    float4* boxes              = (float4*)(ws + WS_BOXES_OFF);
    unsigned* keys             = (unsigned*)(ws + WS_KEYS_OFF);
    unsigned long long* g_cand = (unsigned long long*)(ws + WS_CAND_OFF);
    unsigned long long* g_sort = (unsigned long long*)(ws + WS_SORT_OFF);
    float4* g_sbox             = (float4*)(ws + WS_SBOX_OFF);
    int* g_keep                = (int*)(ws + WS_KEEP_OFF);
    int* g_meta                = (int*)(ws + WS_META_OFF);

    int top_k = out_size / 8;
    if (top_k > MAX_TOPK) top_k = MAX_TOPK;

    const unsigned zero_arg = 0u;   // runtime zero, opaque to device compiler

    decode_kernel<<<N_BOX / 256, 256, 0, stream>>>(x, y, anchors, boxes, keys, zero_arg);
    select_kernel<<<1, NT, 0, stream>>>(keys, g_cand, g_meta, zero_arg);
    sortgather_kernel<<<1, NT, 0, stream>>>(g_cand, boxes, g_sort, g_sbox, g_meta, zero_arg);
    nms_kernel<<<1, 64, 0, stream>>>(g_sort, g_sbox, g_keep, g_meta, top_k, zero_arg);
    output_kernel<<<1, NT, 0, stream>>>(x, y, anchors, g_keep, g_meta, out, top_k, zero_arg);
}

// Round 8
// 44.202 us; speedup vs baseline: 9.2699x; 9.2699x over previous
//
#include <hip/hip_runtime.h>
#include <math.h>

#define N_BOX 8192
#define NT 1024
#define TOPK_CAP 128
#define IOU_THR 0.3f
#define M_TARGET 224u
#define CAP_C 256            // max candidates after refinement (4 u64 alive words)
#define NWORDS 4
#define CHUNK_ROWS 128
#define BIN1_SHIFT 19        // pass A: top 13 bits
#define BIN2_SHIFT 6         // pass B: bits [6,19)

// ws layout: [0,128K) float4 boxes[8192]; [128K,160K) u32 keys[8192]
#define WS_BOXES_OFF 0
#define WS_KEYS_OFF  (N_BOX * 16)

// ---------------- K1: decode + 32-bit sort-key build ----------------
__global__ void decode_kernel(const float* __restrict__ x,
                              const float* __restrict__ y,
                              const float* __restrict__ anchors,
                              float4* __restrict__ boxes,
                              unsigned* __restrict__ keys)
{
#pragma clang fp contract(off)
    int i = blockIdx.x * blockDim.x + threadIdx.x;
    if (i >= N_BOX) return;

    float s = 1.0f / (1.0f + expf(-x[i]));
    keys[i] = ~(__float_as_uint(s) | 0x80000000u);   // asc key = desc score

    const float inv128 = 0.0078125f;
    const float2* yr = (const float2*)(y + i * 18);
    float2 ya = yr[0];
    float2 yb = yr[1];
    float2 an = ((const float2*)anchors)[i];
    float cx = ya.x * inv128 + an.x;
    float cy = ya.y * inv128 + an.y;
    float w2 = (yb.x * inv128) * 0.5f;
    float h2 = (yb.y * inv128) * 0.5f;
    boxes[i] = make_float4(cx - w2, cy - h2, cx + w2, cy + h2);
}

// bits j>iG within word w (64-col window); clears j<=iG (incl. self)
__device__ __forceinline__ unsigned long long upper_mask_u64(int iG, int w) {
    int d = iG - (w << 6);
    if (d < 0) return ~0ull;
    if (d >= 63) return 0ull;
    return ~((2ull << d) - 1ull);
}

// find bin where cumulative count crosses `target` over s_hist[8192]
// out: s_scanout[0]=bin, [1]=cum incl bin, [2]=cum excl bin
__device__ __forceinline__ void hist_scan(unsigned* s_hist, unsigned* s_waveexcl,
                                          unsigned* s_scanout, unsigned target,
                                          int tid, int lane, int wv)
{
    uint4 h0 = ((const uint4*)s_hist)[tid * 2 + 0];
    uint4 h1 = ((const uint4*)s_hist)[tid * 2 + 1];
    unsigned binv[8] = {h0.x, h0.y, h0.z, h0.w, h1.x, h1.y, h1.z, h1.w};
    unsigned csum = binv[0] + binv[1] + binv[2] + binv[3]
                  + binv[4] + binv[5] + binv[6] + binv[7];
    unsigned incl = csum;
    for (int off = 1; off < 64; off <<= 1) {
        unsigned n = __shfl_up(incl, off);
        if (lane >= off) incl += n;
    }
    if (lane == 63) s_waveexcl[wv + 1] = incl;
    __syncthreads();
    if (wv == 0) {
        unsigned t = (lane < 16) ? s_waveexcl[lane + 1] : 0u;
        unsigned v = t;
        for (int off = 1; off < 16; off <<= 1) {
            unsigned n = __shfl_up(v, off);
            if (lane >= off) v += n;
        }
        if (lane < 16) s_waveexcl[lane] = v - t;
    }
    __syncthreads();
    unsigned myexcl = s_waveexcl[wv] + incl - csum;
    if (myexcl < target && myexcl + csum >= target) {
        unsigned run = myexcl;
#pragma unroll
        for (int k = 0; k < 8; k++) {
            run += binv[k];
            if (run >= target) {
                s_scanout[0] = (unsigned)(tid * 8 + k);
                s_scanout[1] = run;
                s_scanout[2] = run - binv[k];
                break;
            }
        }
    }
    __syncthreads();
}

// ---------------- K2: select(2-level) + sort + bitmask NMS + output ----------------
__global__ __launch_bounds__(NT)
void topk_nms_kernel(const float* __restrict__ x,
                     const float* __restrict__ y,
                     const float* __restrict__ anchors,
                     const unsigned* __restrict__ keys,
                     const float4* __restrict__ boxes,
                     float* __restrict__ out,
                     int top_k)
{
#pragma clang fp contract(off)
    __shared__ unsigned s_hist[N_BOX];                        // 32 KB
    __shared__ unsigned s_waveexcl[17];
    __shared__ unsigned s_scanout[3];
    __shared__ unsigned long long s_cand[CAP_C];              // 2 KB
    __shared__ unsigned long long s_sorted[CAP_C];            // 2 KB
    __shared__ float4 s_sbox[CAP_C];                          // 4 KB
    __shared__ unsigned long long s_mrow[CHUNK_ROWS][NWORDS]; // 4 KB
    __shared__ unsigned long long s_rnz[2];
    __shared__ short s_keeppos[TOPK_CAP];
    __shared__ int s_cnt, s_kept, s_done;

    const int tid = threadIdx.x;
    const int lane = tid & 63;
    const int wv = tid >> 6;

    // ---- load my 8 keys ----
    const uint4* kp = (const uint4*)keys;
    uint4 ka = kp[tid * 2 + 0];
    uint4 kb = kp[tid * 2 + 1];
    unsigned myk[8] = {ka.x, ka.y, ka.z, ka.w, kb.x, kb.y, kb.z, kb.w};

    if (tid == 0) { s_cnt = 0; s_kept = 0; s_done = 0; }
    {
        uint4 z = make_uint4(0u, 0u, 0u, 0u);
        uint4* hp = (uint4*)s_hist;
        hp[tid * 2 + 0] = z;
        hp[tid * 2 + 1] = z;
        if (tid < CAP_C) s_cand[tid] = ~0ull;   // pad > any real key
    }
    __syncthreads();

    // ---- pass A: histogram on top 13 bits ----
#pragma unroll
    for (int k = 0; k < 8; k++)
        atomicAdd(&s_hist[myk[k] >> BIN1_SHIFT], 1u);
    __syncthreads();
    hist_scan(s_hist, s_waveexcl, s_scanout, M_TARGET, tid, lane, wv);
    const unsigned B1 = s_scanout[0];
    const unsigned n0 = s_scanout[2];
    __syncthreads();

    // ---- pass B: refine within boundary bin on bits [6,19) ----
    {
        uint4 z = make_uint4(0u, 0u, 0u, 0u);
        uint4* hp = (uint4*)s_hist;
        hp[tid * 2 + 0] = z;
        hp[tid * 2 + 1] = z;
    }
    __syncthreads();
#pragma unroll
    for (int k = 0; k < 8; k++)
        if ((myk[k] >> BIN1_SHIFT) == B1)
            atomicAdd(&s_hist[(myk[k] >> BIN2_SHIFT) & 8191u], 1u);
    __syncthreads();
    hist_scan(s_hist, s_waveexcl, s_scanout, M_TARGET - n0, tid, lane, wv);
    const unsigned B2 = s_scanout[0];
    int C = (int)(n0 + s_scanout[1]);
    if (C > CAP_C) C = CAP_C;

    // ---- compact selected candidates (u64 key<<32|idx, unique) ----
#pragma unroll
    for (int k = 0; k < 8; k++) {
        unsigned kk = myk[k];
        unsigned b1 = kk >> BIN1_SHIFT;
        bool sel = (b1 < B1) || (b1 == B1 && ((kk >> BIN2_SHIFT) & 8191u) <= B2);
        if (sel) {
            int p = atomicAdd(&s_cnt, 1);
            if (p < CAP_C)
                s_cand[p] = (((unsigned long long)kk) << 32) | (unsigned)(tid * 8 + k);
        }
    }
    __syncthreads();

    // ---- rank sort (exact, keys unique), b128 broadcast reads ----
    const int Cpad = (C + 7) & ~7;
    if (tid < C) {
        unsigned long long me = s_cand[tid];
        int rank = 0;
        const ulonglong2* cp = (const ulonglong2*)s_cand;
        for (int j = 0; j < Cpad; j += 8) {
            ulonglong2 a = cp[(j >> 1) + 0];
            ulonglong2 b = cp[(j >> 1) + 1];
            ulonglong2 d = cp[(j >> 1) + 2];
            ulonglong2 e = cp[(j >> 1) + 3];
            rank += (a.x < me) + (a.y < me) + (b.x < me) + (b.y < me)
                  + (d.x < me) + (d.y < me) + (e.x < me) + (e.y < me);
        }
        s_sorted[rank] = me;
    }
    __syncthreads();

    // ---- gather candidate boxes; pad with far zero-area sentinels ----
    if (tid < CAP_C) {
        if (tid < C)
            s_sbox[tid] = boxes[(unsigned)(s_sorted[tid] & 0xFFFFFFFFull)];
        else
            s_sbox[tid] = make_float4(3e30f, 3e30f, 3e30f, 3e30f);
    }
    __syncthreads();

    // ---- bitmask NMS: lane l<4 of wave 0 holds alive word l ----
    unsigned long long aliveW = 0ull;
    if (wv == 0 && lane < NWORDS) {
        int nb = C - (lane << 6);
        aliveW = (nb >= 64) ? ~0ull : ((nb <= 0) ? 0ull : ((1ull << nb) - 1ull));
    }
    const int topk = top_k;

    for (int cb = 0; cb < C; cb += CHUNK_ROWS) {
        if (tid < 2) s_rnz[tid] = 0ull;
        __syncthreads();

        // build suppression rows [cb, cb+128): 256 threads, 2 rows x 1 word each
        if (tid < 256) {
            int w = tid & 3;
            int rg = tid >> 2;                  // 0..63
            int rl0 = rg * 2, rl1 = rl0 + 1;
            int iG0 = cb + rl0, iG1 = cb + rl1;
            float4 A0 = s_sbox[iG0];
            float4 A1 = s_sbox[iG1];
            float a0 = (A0.z - A0.x) * (A0.w - A0.y);
            float a1 = (A1.z - A1.x) * (A1.w - A1.y);
            unsigned long long bits0 = 0ull, bits1 = 0ull;
            for (int k = 0; k < 64; ++k) {
                int kk = (k + 2 * w) & 63;      // bank stagger across w
                float4 Bx = s_sbox[(w << 6) + kk];
                float ba = (Bx.z - Bx.x) * (Bx.w - Bx.y);
                float iw0 = fmaxf(fminf(A0.z, Bx.z) - fmaxf(A0.x, Bx.x), 0.0f);
                float ih0 = fmaxf(fminf(A0.w, Bx.w) - fmaxf(A0.y, Bx.y), 0.0f);
                float in0 = iw0 * ih0;
                float iou0 = in0 / (a0 + ba - in0);
                if (iou0 > IOU_THR) bits0 |= (1ull << kk);
                float iw1 = fmaxf(fminf(A1.z, Bx.z) - fmaxf(A1.x, Bx.x), 0.0f);
                float ih1 = fmaxf(fminf(A1.w, Bx.w) - fmaxf(A1.y, Bx.y), 0.0f);
                float in1 = iw1 * ih1;
                float iou1 = in1 / (a1 + ba - in1);
                if (iou1 > IOU_THR) bits1 |= (1ull << kk);
            }
            bits0 &= upper_mask_u64(iG0, w);
            bits1 &= upper_mask_u64(iG1, w);
            s_mrow[rl0][w] = bits0;
            s_mrow[rl1][w] = bits1;
            unsigned long long nz = 0ull;
            if (bits0) nz |= 1ull << (rl0 & 63);
            if (bits1) nz |= 1ull << (rl1 & 63);
            if (nz) atomicOr(&s_rnz[rl0 >> 6], nz);
        }
        __syncthreads();

        // greedy scan of this chunk's 128 bits (wave 0, register-resident)
        if (wv == 0) {
            const int w0i = cb >> 6;
            unsigned long long cw0 = __shfl(aliveW, w0i);
            unsigned long long cw1 = __shfl(aliveW, w0i + 1);
            unsigned long long rnz0 = s_rnz[0];
            unsigned long long rnz1 = s_rnz[1];
            int kept = s_kept;

            while (kept < topk && cw0 != 0ull) {
                int b = __builtin_ctzll(cw0);
                if (lane == 0) s_keeppos[kept] = (short)(cb + b);
                kept++;
                if (kept >= topk) break;
                if ((rnz0 >> b) & 1ull) {
                    if (lane < NWORDS) aliveW &= ~s_mrow[b][lane];
                    cw0 = __shfl(aliveW, w0i) & ~((2ull << b) - 1ull);
                    cw1 = __shfl(aliveW, w0i + 1);
                } else {
                    cw0 &= cw0 - 1ull;
                }
            }
            while (kept < topk && cw1 != 0ull) {
                int b = __builtin_ctzll(cw1);
                if (lane == 0) s_keeppos[kept] = (short)(cb + 64 + b);
                kept++;
                if (kept >= topk) break;
                if ((rnz1 >> b) & 1ull) {
                    if (lane < NWORDS) aliveW &= ~s_mrow[64 + b][lane];
                    cw1 = __shfl(aliveW, w0i + 1) & ~((2ull << b) - 1ull);
                } else {
                    cw1 &= cw1 - 1ull;
                }
            }
            if (lane == 0) {
                s_kept = kept;
                if (kept >= topk) s_done = 1;
            }
        }
        __syncthreads();
        if (s_done) break;
    }

    // ---- output: [score, det0, det1, det2, det4, det5, det8, det9] ----
    const float inv128 = 0.0078125f;
    const int nkept = s_kept;
    const int total = topk * 8;
    for (int t = tid; t < total; t += NT) {
        int r = t >> 3;
        int col = t & 7;
        float v = 0.0f;
        if (r < nkept) {
            int pos = (int)s_keeppos[r];
            int idx = (int)(unsigned)(s_sorted[pos] & 0xFFFFFFFFull);
            if (col == 0) {
                v = 1.0f / (1.0f + expf(-x[idx]));
            } else {
                int j = (col <= 3) ? (col - 1) : ((col <= 5) ? col : (col + 2));
                float a;
                if (j == 2) a = 0.0f;
                else        a = (j & 1) ? anchors[idx * 2 + 1] : anchors[idx * 2 + 0];
                v = y[idx * 18 + j] * inv128 + a;
            }
        }
        out[t] = v;
    }
}

extern "C" void kernel_launch(void* const* d_in, const int* in_sizes, int n_in,
                              void* d_out, int out_size, void* d_ws, size_t ws_size,
                              hipStream_t stream) {
    const float* x       = (const float*)d_in[0];   // (1, 8192, 1)
    const float* y       = (const float*)d_in[1];   // (1, 8192, 18)
    const float* anchors = (const float*)d_in[2];   // (8192, 2)
    float* out = (float*)d_out;                     // (top_k, 8) f32

    float4* boxes  = (float4*)((char*)d_ws + WS_BOXES_OFF);
    unsigned* keys = (unsigned*)((char*)d_ws + WS_KEYS_OFF);

    int top_k = out_size / 8;
    if (top_k > TOPK_CAP) top_k = TOPK_CAP;

    decode_kernel<<<N_BOX / 256, 256, 0, stream>>>(x, y, anchors, boxes, keys);
    topk_nms_kernel<<<1, NT, 0, stream>>>(x, y, anchors, keys, boxes, out, top_k);
}